// Round 12
// baseline (479.355 us; speedup 1.0000x reference)
//
#include <hip/hip_runtime.h>
#include <hip/hip_cooperative_groups.h>

namespace cg = cooperative_groups;

#define N_NODES 50000
#define IN_SIZE 512
#define HID 128
#define OUT 64
#define NB 256                 // edge-partition blocks (hist/scatter)
#define SHIFT 7                // bucket = dst >> 7  (128 nodes per bucket)
#define NBUCK 391              // ceil(50000/128)
#define NBINS8 12500           // 50000 uint8 bins packed in uint32 (50KB LDS)

typedef _Float16 f16x8 __attribute__((ext_vector_type(8)));
typedef _Float16 f16x4 __attribute__((ext_vector_type(4)));
typedef float    f32x4 __attribute__((ext_vector_type(4)));

// ---------- inline int64-vs-int32 layout detection ----------
__device__ __forceinline__ bool detect_w(const int* p, int t, int* sh) {
    if (t < 64) {
        unsigned long long m = __ballot(p[2 * t + 1] == 0);
        if (t == 0) *sh = (m == ~0ull) ? 1 : 0;
    }
    __syncthreads();
    return *sh != 0;
}

__device__ __forceinline__ int load_idx(const void* p, int e, bool w) {
    return w ? (int)((const long long*)p)[e] : ((const int*)p)[e];
}

// ---------- fused CSR build (cooperative, 391 blocks x 256 thr, 5 phases) ----------
// Phase bodies are byte-level copies of the R10-verified kernels:
//  P1  b<256: dst-coarse hist + packed-u8 src hist (spart). b>=256: weight transpose (concurrent).
//  P2  all: scanA (bucket-major exclusive scan of hist).
//  P3  b==0: scanB over 391 bucket sums (512-slot ping-pong scan).
//  P4  b<256: coarse scatter tmp = (src | dl<<16).
//  P5  all: fine count+scan+scatter -> rp/esrc/innorm, + spart reduce -> onorm.
// LDS union ~61KB -> 2 blocks/CU -> cooperative capacity 512 >= 391. grid.sync() x4, uniform.
__global__ __launch_bounds__(256) void k_csr_coop(const void* __restrict__ srcp,
                                                  const void* __restrict__ dstp,
                                                  int* __restrict__ hist,
                                                  unsigned int* __restrict__ spart,
                                                  int E, int EPB,
                                                  const float* __restrict__ W1, _Float16* __restrict__ W1T,
                                                  const float* __restrict__ W2, _Float16* __restrict__ W2T,
                                                  int* __restrict__ bsum, int* __restrict__ bb,
                                                  int* __restrict__ rp, unsigned int* __restrict__ tmp,
                                                  int* __restrict__ esrc,
                                                  float* __restrict__ innorm, float* __restrict__ onorm) {
    cg::grid_group grid = cg::this_grid();
    __shared__ unsigned int sbins[NBINS8];   // 50 KB (P1); dead after
    __shared__ int dbins[NBUCK];             // P1 dbins / P4 cur
    __shared__ int shw;
    __shared__ int s1[256];                  // P2 scan
    __shared__ int ping[512], pong[512];     // P3 scan
    __shared__ int fcnt[128], sc[128], fcur[128];  // P5
    __shared__ int rs[256][4];               // P5 spart reduce
    const int t = threadIdx.x, b = blockIdx.x;
    bool w = false;

    // ---- P1 ----
    if (b < NB) {
        for (int i = t; i < NBINS8; i += 256) sbins[i] = 0;
        for (int i = t; i < NBUCK; i += 256) dbins[i] = 0;
        w = detect_w((const int*)dstp, t, &shw);
        __syncthreads();
        int eend = min(E, (b + 1) * EPB);
        for (int e = b * EPB + t; e < eend; e += 256) {
            int s = load_idx(srcp, e, w);
            int d = load_idx(dstp, e, w);
            atomicAdd(&dbins[d >> SHIFT], 1);
            atomicAdd(&sbins[s >> 2], 1u << ((s & 3) << 3));
        }
        __syncthreads();
        for (int i = t; i < NBUCK; i += 256) hist[i * NB + b] = dbins[i];
        for (int i = t; i < NBINS8; i += 256) spart[(size_t)b * NBINS8 + i] = sbins[i];
    } else {
        // weight transpose, grid-stride over blocks 256..390
        const int total = IN_SIZE * HID + HID * OUT;
        for (int i = (b - NB) * 256 + t; i < total; i += (NBUCK - NB) * 256) {
            if (i < IN_SIZE * HID) {
                int k = i >> 7, n = i & (HID - 1);
                W1T[(size_t)n * IN_SIZE + k] = (_Float16)W1[i];
            } else {
                int j = i - IN_SIZE * HID;
                int k = j >> 6, n = j & (OUT - 1);
                W2T[(size_t)n * HID + k] = (_Float16)W2[j];
            }
        }
    }
    grid.sync();

    // ---- P2: scanA for bucket b ----
    {
        int v = hist[b * NB + t];
        s1[t] = v;
        __syncthreads();
        for (int off = 1; off < 256; off <<= 1) {
            int u = (t >= off) ? s1[t - off] : 0;
            __syncthreads();
            s1[t] += u;
            __syncthreads();
        }
        hist[b * NB + t] = s1[t] - v;
        if (t == 255) bsum[b] = s1[255];
    }
    grid.sync();

    // ---- P3: scanB on block 0 (512 slots, 2/thread, ping-pong) ----
    if (b == 0) {
        int v0 = (t < NBUCK) ? bsum[t] : 0;
        int v1 = (t + 256 < NBUCK) ? bsum[t + 256] : 0;
        ping[t] = v0; ping[t + 256] = v1;
        __syncthreads();
        int* sB = ping; int* dB = pong;
        for (int off = 1; off < 512; off <<= 1) {
            dB[t]       = sB[t]       + ((t >= off) ? sB[t - off] : 0);
            dB[t + 256] = sB[t + 256] + ((t + 256 >= off) ? sB[t + 256 - off] : 0);
            __syncthreads();
            int* tp = sB; sB = dB; dB = tp;
        }
        if (t <= NBUCK) bb[t] = sB[t] - v0;                     // exclusive
        if (t + 256 <= NBUCK) bb[t + 256] = sB[t + 256] - v1;   // bb[NBUCK] = E
    }
    grid.sync();

    // ---- P4: coarse scatter (blocks 0..255) ----
    if (b < NB) {
        for (int i = t; i < NBUCK; i += 256) dbins[i] = hist[i * NB + b] + bb[i];  // cur
        __syncthreads();
        int eend = min(E, (b + 1) * EPB);
        for (int e = b * EPB + t; e < eend; e += 256) {
            int s = load_idx(srcp, e, w);
            int d = load_idx(dstp, e, w);
            int pos = atomicAdd(&dbins[d >> SHIFT], 1);
            tmp[pos] = (unsigned int)s | ((unsigned int)(d & 127) << 16);
        }
    }
    grid.sync();

    // ---- P5: fine (bucket b) ----
    {
        const int u = b;
        const int e0 = bb[u], e1 = bb[u + 1];
        if (t < 128) fcnt[t] = 0;
        __syncthreads();
        for (int e = e0 + t; e < e1; e += 256)
            atomicAdd(&fcnt[tmp[e] >> 16], 1);
        // fused spart reduce: bucket u owns packed words u*32 .. u*32+31 (4 nodes/word)
        {
            const int wrd = t & 31, grp = t >> 5;
            const int wd = u * 32 + wrd;
            int c0 = 0, c1 = 0, c2 = 0, c3 = 0;
            if (wd < NBINS8) {
                for (int p = grp * 32; p < grp * 32 + 32; ++p) {
                    unsigned int v = spart[(size_t)p * NBINS8 + wd];
                    c0 += (int)(v & 255u);
                    c1 += (int)((v >> 8) & 255u);
                    c2 += (int)((v >> 16) & 255u);
                    c3 += (int)(v >> 24);
                }
            }
            rs[t][0] = c0; rs[t][1] = c1; rs[t][2] = c2; rs[t][3] = c3;
        }
        __syncthreads();   // covers fcnt atomics AND rs
        if (t < 32) {
            const int wd = u * 32 + t;
            if (wd < NBINS8) {
                int d0 = 0, d1 = 0, d2 = 0, d3 = 0;
                for (int g = 0; g < 8; ++g) {
                    d0 += rs[g * 32 + t][0]; d1 += rs[g * 32 + t][1];
                    d2 += rs[g * 32 + t][2]; d3 += rs[g * 32 + t][3];
                }
                if (d0 < 1) d0 = 1; if (d1 < 1) d1 = 1;
                if (d2 < 1) d2 = 1; if (d3 < 1) d3 = 1;
                int n0 = 4 * wd;
                if (n0     < N_NODES) onorm[n0]     = 1.0f / sqrtf((float)d0);
                if (n0 + 1 < N_NODES) onorm[n0 + 1] = 1.0f / sqrtf((float)d1);
                if (n0 + 2 < N_NODES) onorm[n0 + 2] = 1.0f / sqrtf((float)d2);
                if (n0 + 3 < N_NODES) onorm[n0 + 3] = 1.0f / sqrtf((float)d3);
            }
        }
        if (t < 128) sc[t] = fcnt[t];
        __syncthreads();
        for (int off = 1; off < 128; off <<= 1) {
            int v = (t < 128 && t >= off) ? sc[t - off] : 0;
            __syncthreads();
            if (t < 128) sc[t] += v;
            __syncthreads();
        }
        if (t < 128) {
            int base = e0 + sc[t] - fcnt[t];
            fcur[t] = base;
            int node = u * 128 + t;
            if (node < N_NODES) {
                rp[node] = base;
                int c = fcnt[t]; if (c < 1) c = 1;
                innorm[node] = 1.0f / sqrtf((float)c);
            }
        }
        if (u == NBUCK - 1 && t == 0) rp[N_NODES] = e1;
        __syncthreads();
        for (int e = e0 + t; e < e1; e += 256) {
            unsigned int p = tmp[e];
            int pos = atomicAdd(&fcur[p >> 16], 1);
            esrc[pos] = (int)(p & 0xFFFFu);
        }
    }
}

// ---------- GEMM1 (MFMA fp16, col-split for TLP, R10-verified): X1 = fp16( onorm * (feat @ W1) ) ----------
#define LDA 44  // 32 + 12 halfs pad (conflict-free, verified R3)
__global__ __launch_bounds__(256) void k_gemm1_mfma(const float* __restrict__ A,
                                                    const _Float16* __restrict__ BT,
                                                    const float* __restrict__ onorm,
                                                    _Float16* __restrict__ X) {
    __shared__ _Float16 As[2][64 * LDA];
    __shared__ _Float16 Bs[2][64 * LDA];
    const int tid  = threadIdx.x;
    const int wave = tid >> 6, lane = tid & 63;
    const int lm = lane & 15, lq = lane >> 4;
    const int row0 = (blockIdx.x >> 1) * 64;
    const int ch   = (blockIdx.x & 1) * 64;   // output col offset (HID half)

    const int ar = tid >> 2, aq = tid & 3;
    int arow = row0 + ar; if (arow >= N_NODES) arow = N_NODES - 1;
    const float* aptr = A + (size_t)arow * IN_SIZE + aq * 8;
    const int bn = tid >> 2, bq = tid & 3;
    const _Float16* bptr = BT + (size_t)(ch + bn) * IN_SIZE + bq * 8;

    f32x4 acc[4];
#pragma unroll
    for (int nt = 0; nt < 4; ++nt) acc[nt] = (f32x4){0.f, 0.f, 0.f, 0.f};

    {
        float4 a0 = *(const float4*)(aptr);
        float4 a1 = *(const float4*)(aptr + 4);
        f16x8  b0 = *(const f16x8*)(bptr);
        f16x8 ap = {(_Float16)a0.x, (_Float16)a0.y, (_Float16)a0.z, (_Float16)a0.w,
                    (_Float16)a1.x, (_Float16)a1.y, (_Float16)a1.z, (_Float16)a1.w};
        *(f16x8*)&As[0][ar * LDA + aq * 8] = ap;
        *(f16x8*)&Bs[0][bn * LDA + bq * 8] = b0;
    }
    __syncthreads();

#pragma unroll
    for (int kt = 0; kt < IN_SIZE / 32; ++kt) {
        const int k0 = kt * 32;
        const int cur = kt & 1;
        float4 na0, na1; f16x8 nb0;
        const bool more = (k0 + 32) < IN_SIZE;
        if (more) {
            na0 = *(const float4*)(aptr + k0 + 32);
            na1 = *(const float4*)(aptr + k0 + 36);
            nb0 = *(const f16x8*)(bptr + k0 + 32);
        }
        f16x8 af = *(const f16x8*)&As[cur][(wave * 16 + lm) * LDA + lq * 8];
#pragma unroll
        for (int nt = 0; nt < 4; ++nt) {
            f16x8 bf = *(const f16x8*)&Bs[cur][(nt * 16 + lm) * LDA + lq * 8];
            acc[nt] = __builtin_amdgcn_mfma_f32_16x16x32_f16(af, bf, acc[nt], 0, 0, 0);
        }
        if (more) {
            f16x8 ap = {(_Float16)na0.x, (_Float16)na0.y, (_Float16)na0.z, (_Float16)na0.w,
                        (_Float16)na1.x, (_Float16)na1.y, (_Float16)na1.z, (_Float16)na1.w};
            *(f16x8*)&As[cur ^ 1][ar * LDA + aq * 8] = ap;
            *(f16x8*)&Bs[cur ^ 1][bn * LDA + bq * 8] = nb0;
            __syncthreads();
        }
    }
#pragma unroll
    for (int i = 0; i < 4; ++i) {
        int row = row0 + wave * 16 + lq * 4 + i;
        if (row < N_NODES) {
            float on = onorm[row];
            _Float16* o = X + (size_t)row * HID + ch + lm;
#pragma unroll
            for (int nt = 0; nt < 4; ++nt)
                o[nt * 16] = (_Float16)(acc[nt][i] * on);
        }
    }
}

// ---------- agg1 + fused GEMM2 (R10-verified): X2 = fp16( H @ W2 ) ----------
#define LDH 136  // 128 + 8 halfs pad
__global__ __launch_bounds__(256) void k_agg1_fused(const _Float16* __restrict__ X, const int* __restrict__ rp,
                                                    const int* __restrict__ esrc, const float* __restrict__ innorm,
                                                    const float* __restrict__ onorm, const float* __restrict__ b1,
                                                    const _Float16* __restrict__ W2T, _Float16* __restrict__ X2) {
    __shared__ _Float16 Hs[16 * LDH];
    const int t = threadIdx.x;
    const int ln = t >> 4;
    const int c  = (t & 15) << 3;
    const int n  = blockIdx.x * 16 + ln;
    const int e0 = rp[n], e1 = rp[n + 1];
    float a[8] = {0.f, 0.f, 0.f, 0.f, 0.f, 0.f, 0.f, 0.f};
    int e = e0;
    for (; e + 3 < e1; e += 4) {
        int s0 = esrc[e], s1 = esrc[e + 1], s2 = esrc[e + 2], s3 = esrc[e + 3];
        f16x8 v0 = *(const f16x8*)&X[(size_t)s0 * HID + c];
        f16x8 v1 = *(const f16x8*)&X[(size_t)s1 * HID + c];
        f16x8 v2 = *(const f16x8*)&X[(size_t)s2 * HID + c];
        f16x8 v3 = *(const f16x8*)&X[(size_t)s3 * HID + c];
#pragma unroll
        for (int j = 0; j < 8; ++j)
            a[j] += ((float)v0[j] + (float)v1[j]) + ((float)v2[j] + (float)v3[j]);
    }
    for (; e < e1; ++e) {
        f16x8 v = *(const f16x8*)&X[(size_t)esrc[e] * HID + c];
#pragma unroll
        for (int j = 0; j < 8; ++j) a[j] += (float)v[j];
    }
    const float inn = innorm[n], on = onorm[n];
    float4 bA = *(const float4*)&b1[c];
    float4 bB = *(const float4*)&b1[c + 4];
    const float bv[8] = {bA.x, bA.y, bA.z, bA.w, bB.x, bB.y, bB.z, bB.w};
    f16x8 h;
#pragma unroll
    for (int j = 0; j < 8; ++j)
        h[j] = (_Float16)(fmaxf(a[j] * inn + bv[j], 0.f) * on);
    *(f16x8*)&Hs[ln * LDH + c] = h;
    __syncthreads();

    const int wave = t >> 6, lane = t & 63;
    const int lm = lane & 15, lq = lane >> 4;
    f32x4 acc = (f32x4){0.f, 0.f, 0.f, 0.f};
#pragma unroll
    for (int k0 = 0; k0 < HID; k0 += 32) {
        f16x8 af = *(const f16x8*)&Hs[lm * LDH + k0 + lq * 8];
        f16x8 bf = *(const f16x8*)&W2T[(size_t)(wave * 16 + lm) * HID + k0 + lq * 8];
        acc = __builtin_amdgcn_mfma_f32_16x16x32_f16(af, bf, acc, 0, 0, 0);
    }
    const int n0 = blockIdx.x * 16;
#pragma unroll
    for (int i = 0; i < 4; ++i) {
        int row = n0 + lq * 4 + i;
        X2[(size_t)row * OUT + wave * 16 + lm] = (_Float16)acc[i];
    }
}

// ---------- agg2 (R10-verified): out = gather-sum(X2)*in_norm + b2 ----------
__global__ __launch_bounds__(256) void k_agg2(const _Float16* __restrict__ X2, const int* __restrict__ rp,
                                              const int* __restrict__ esrc, const float* __restrict__ innorm,
                                              const float* __restrict__ b2, float* __restrict__ out) {
    const int n = blockIdx.x * 32 + (threadIdx.x >> 3);
    const int c = (threadIdx.x & 7) << 3;
    if (n >= N_NODES) return;
    const int e0 = rp[n], e1 = rp[n + 1];
    float a[8] = {0.f, 0.f, 0.f, 0.f, 0.f, 0.f, 0.f, 0.f};
    int e = e0;
    for (; e + 3 < e1; e += 4) {
        int s0 = esrc[e], s1 = esrc[e + 1], s2 = esrc[e + 2], s3 = esrc[e + 3];
        f16x8 v0 = *(const f16x8*)&X2[(size_t)s0 * OUT + c];
        f16x8 v1 = *(const f16x8*)&X2[(size_t)s1 * OUT + c];
        f16x8 v2 = *(const f16x8*)&X2[(size_t)s2 * OUT + c];
        f16x8 v3 = *(const f16x8*)&X2[(size_t)s3 * OUT + c];
#pragma unroll
        for (int j = 0; j < 8; ++j)
            a[j] += ((float)v0[j] + (float)v1[j]) + ((float)v2[j] + (float)v3[j]);
    }
    for (; e < e1; ++e) {
        f16x8 v = *(const f16x8*)&X2[(size_t)esrc[e] * OUT + c];
#pragma unroll
        for (int j = 0; j < 8; ++j) a[j] += (float)v[j];
    }
    const float inn = innorm[n];
    float4 bA = *(const float4*)&b2[c];
    float4 bB = *(const float4*)&b2[c + 4];
    float* o = out + (size_t)n * OUT + c;
    *(float4*)o       = make_float4(a[0] * inn + bA.x, a[1] * inn + bA.y,
                                    a[2] * inn + bA.z, a[3] * inn + bA.w);
    *(float4*)(o + 4) = make_float4(a[4] * inn + bB.x, a[5] * inn + bB.y,
                                    a[6] * inn + bB.z, a[7] * inn + bB.w);
}

extern "C" void kernel_launch(void* const* d_in, const int* in_sizes, int n_in,
                              void* d_out, int out_size, void* d_ws, size_t ws_size,
                              hipStream_t stream) {
    const float* feat = (const float*)d_in[0];
    const float* W1   = (const float*)d_in[1];
    const float* b1   = (const float*)d_in[2];
    const float* W2   = (const float*)d_in[3];
    const float* b2   = (const float*)d_in[4];
    const void*  srcp = (const void*)d_in[5];
    const void*  dstp = (const void*)d_in[6];
    const int    E    = in_sizes[5];
    float* out = (float*)d_out;

    char* w = (char*)d_ws;
    size_t off = 0;
    auto alloc = [&](size_t bytes) -> void* {
        off = (off + 255) & ~(size_t)255;
        void* p = w + off;
        off += bytes;
        return p;
    };
    int*   hist    = (int*)alloc((size_t)NBUCK * NB * 4);
    int*   bsum    = (int*)alloc((size_t)NBUCK * 4);
    int*   bb      = (int*)alloc((size_t)(NBUCK + 1) * 4);
    int*   rp      = (int*)alloc((size_t)(N_NODES + 1) * 4);
    unsigned int* spart = (unsigned int*)alloc((size_t)NB * NBINS8 * 4);
    unsigned int* tmp   = (unsigned int*)alloc((size_t)E * 4);
    int*   esrc    = (int*)alloc((size_t)E * 4);
    float* onorm   = (float*)alloc((size_t)N_NODES * 4);
    float* innorm  = (float*)alloc((size_t)N_NODES * 4);
    _Float16* W1T  = (_Float16*)alloc((size_t)IN_SIZE * HID * 2);
    _Float16* W2T  = (_Float16*)alloc((size_t)HID * OUT * 2);
    _Float16* X1   = (_Float16*)alloc((size_t)N_NODES * HID * 2);
    _Float16* X2   = (_Float16*)alloc((size_t)N_NODES * OUT * 2);
    (void)ws_size; (void)n_in; (void)out_size;

    int EPB = (E + NB - 1) / NB;
    int Ev  = E;

    // CSR build: one cooperative kernel (5 phases, 4 grid.sync)
    void* cargs[] = {(void*)&srcp, (void*)&dstp, (void*)&hist, (void*)&spart,
                     (void*)&Ev, (void*)&EPB,
                     (void*)&W1, (void*)&W1T, (void*)&W2, (void*)&W2T,
                     (void*)&bsum, (void*)&bb, (void*)&rp, (void*)&tmp, (void*)&esrc,
                     (void*)&innorm, (void*)&onorm};
    hipLaunchCooperativeKernel((const void*)k_csr_coop, dim3(NBUCK), dim3(256),
                               cargs, 0, stream);

    // dense + aggregation pipeline
    k_gemm1_mfma<<<((N_NODES + 63) / 64) * 2, 256, 0, stream>>>(feat, W1T, onorm, X1);
    k_agg1_fused<<<(N_NODES + 15) / 16, 256, 0, stream>>>(X1, rp, esrc, innorm, onorm, b1, W2T, X2);
    k_agg2<<<(N_NODES + 31) / 32, 256, 0, stream>>>(X2, rp, esrc, innorm, b2, out);
}